// Round 3
// baseline (845.353 us; speedup 1.0000x reference)
//
#include <hip/hip_runtime.h>

#define TOK   32768
#define DM    768
#define KDIM  768
#define LSEQ  4096
#define NC    64
#define CL    64
#define NCHAIN 6144

typedef __bf16 bf16x8 __attribute__((ext_vector_type(8)));
typedef float  f32x4  __attribute__((ext_vector_type(4)));
typedef unsigned short u16;
typedef unsigned int u32;

__device__ __forceinline__ u16 f2bf(float f) {
  unsigned u = __builtin_bit_cast(unsigned, f);
  u += 0x7fffu + ((u >> 16) & 1u);
  return (u16)(u >> 16);
}
__device__ __forceinline__ float bf2f(u32 h) {
  unsigned u = (h & 0xffffu) << 16;
  return __builtin_bit_cast(float, u);
}

#define GLOAD_LDS16(g, l) __builtin_amdgcn_global_load_lds( \
    (const __attribute__((address_space(1))) void*)(g),     \
    (__attribute__((address_space(3))) void*)(l), 16, 0, 0)

// ---------------- fp32 -> bf16 weight convert ----------------
__global__ void cvt_k(const float* __restrict__ src, u16* __restrict__ dst, int n) {
  int i = blockIdx.x * 256 + threadIdx.x;
  if (i < n) dst[i] = f2bf(src[i]);
}

// ---------------- W_dt = dt_proj_w (768x48) @ x_proj_w[:48] (48x768) -> bf16 ----------------
__global__ __launch_bounds__(256)
void wdt_k(const float* __restrict__ dtw, const float* __restrict__ xw,
           u16* __restrict__ W) {
  int i = blockIdx.x;
  int j = threadIdx.x;
  float a0 = 0.f, a1 = 0.f, a2 = 0.f;
  for (int r = 0; r < 48; ++r) {
    float d = dtw[i * 48 + r];
    const float* xr = xw + r * DM;
    a0 += d * xr[j];
    a1 += d * xr[j + 256];
    a2 += d * xr[j + 512];
  }
  W[i * DM + j]       = f2bf(a0);
  W[i * DM + j + 256] = f2bf(a1);
  W[i * DM + j + 512] = f2bf(a2);
}

// ---------------- RMSNorm: x (fp32) -> xn (bf16), float4 path ----------------
__global__ __launch_bounds__(192)
void rmsnorm_k(const float* __restrict__ x, const float* __restrict__ w,
               u16* __restrict__ xnb) {
  long t = blockIdx.x;
  int tid = threadIdx.x;
  float4 v = ((const float4*)x)[t * 192 + tid];
  float s = v.x * v.x + v.y * v.y + v.z * v.z + v.w * v.w;
#pragma unroll
  for (int o = 32; o; o >>= 1) s += __shfl_down(s, o, 64);
  __shared__ float red[3];
  if ((tid & 63) == 0) red[tid >> 6] = s;
  __syncthreads();
  float sc = rsqrtf((red[0] + red[1] + red[2]) * (1.f / 768.f) + 1e-6f);
  float4 ww = ((const float4*)w)[tid];
  ushort4 o;
  o.x = f2bf(v.x * sc * ww.x);
  o.y = f2bf(v.y * sc * ww.y);
  o.z = f2bf(v.z * sc * ww.z);
  o.w = f2bf(v.w * sc * ww.w);
  ((ushort4*)xnb)[t * 192 + tid] = o;
}

// ---------------- 256x256 MFMA GEMM, BK=64, 4 phases/K-step, dist-6 prefetch ----
// C[m][n] = sum_k A[m][k]*B[n][k]; A,B bf16 row-major stride KDIM=768. NT=12.
// LDS 128KB: region(p,kh,isB) = ((p*2+kh)*16384 + isB*65536); region = 256 rows x 64B,
// 16B slot swizzle: phys slot = logical ^ ((row>>1)&3), applied on global SOURCE
// (gload_lds writes linearly) and on ds_read address. Stage = 1 half-region K-half,
// 2 gload_lds/thread. Stage schedule: (t,p0):A_k1(t+1) (t,p1):B_k1(t+1)
// (t,p2):A_k0(t+2) (t,p3):B_k0(t+2); waits vmcnt(8) at p1/p3 (0 in last 2 steps).
// EPI: 0 fp32 C; 1 in_proj (conv+silu->o0, silu(z)->o1); 2 bias+softplus->o0 bf16.
template <int EPI>
__global__ __launch_bounds__(512, 2)
void gemm256(const u16* __restrict__ A, const u16* __restrict__ B,
             float* __restrict__ C,
             const float* __restrict__ w0, const float* __restrict__ w1,
             u16* __restrict__ o0, u16* __restrict__ o1) {
  __shared__ __align__(16) char smc[131072];
  const int tid  = threadIdx.x;
  const int lane = tid & 63;
  const int wid  = tid >> 6;
  const int wm   = wid >> 2;   // 0..1
  const int wn   = wid & 3;    // 0..3
  const long rowBase = (long)blockIdx.y * 256;
  const long colBase = (long)blockIdx.x * 256;

  const int srow  = tid >> 2;                       // 0..127
  const int slotl = (tid & 3) ^ ((tid >> 3) & 3);   // source pre-swizzle
  const u16* gA = A + (rowBase + srow) * KDIM + slotl * 8;
  const u16* gB = B + (colBase + srow) * KDIM + slotl * 8;
  const int dstOff = tid * 16;

  const int l15  = lane & 15;
  const int hi   = lane >> 4;
  const int rdK  = ((hi ^ ((l15 >> 1) & 3)) * 16);  // swizzled 16B slot on read

  f32x4 acc[8][4] = {};
  constexpr int NT = KDIM / 64;  // 12

  auto STAGE = [&](const u16* g, int t, int kh, int isB) {
    char* dst = smc + ((t & 1) * 2 + kh) * 16384 + isB * 65536 + dstOff;
    const u16* src = g + (long)t * 64 + kh * 32;
    GLOAD_LDS16(src, dst);
    GLOAD_LDS16(src + 128 * KDIM, dst + 8192);
  };
  auto RD_A = [&](int t, int kh, int fh, bf16x8* av) {
    const char* rg = smc + ((t & 1) * 2 + kh) * 16384;
#pragma unroll
    for (int f = 0; f < 4; ++f)
      av[f] = *(const bf16x8*)(rg + (wm * 128 + fh * 64 + f * 16 + l15) * 64 + rdK);
  };
  auto RD_B = [&](int t, int kh, bf16x8* bv) {
    const char* rg = smc + ((t & 1) * 2 + kh) * 16384 + 65536;
#pragma unroll
    for (int f = 0; f < 4; ++f)
      bv[f] = *(const bf16x8*)(rg + (wn * 64 + f * 16 + l15) * 64 + rdK);
  };

  // prologue: step0 all 4 half-tiles + step1 k0 halves
  STAGE(gA, 0, 0, 0); STAGE(gB, 0, 0, 1);
  STAGE(gA, 0, 1, 0); STAGE(gB, 0, 1, 1);
  STAGE(gA, 1, 0, 0); STAGE(gB, 1, 0, 1);
  asm volatile("s_waitcnt vmcnt(8)" ::: "memory");  // step0 k0 landed
  __builtin_amdgcn_s_barrier();

  for (int t = 0; t < NT; ++t) {
    bf16x8 av[4], bv[4];
    // ---- phase 0: (fh=0, kh=0) ----
    RD_A(t, 0, 0, av); RD_B(t, 0, bv);
    if (t + 1 < NT) STAGE(gA, t + 1, 1, 0);
    __builtin_amdgcn_s_barrier();
    asm volatile("s_waitcnt lgkmcnt(0)" ::: "memory");
    __builtin_amdgcn_s_setprio(1);
#pragma unroll
    for (int f = 0; f < 4; ++f)
#pragma unroll
      for (int b2 = 0; b2 < 4; ++b2)
        acc[f][b2] = __builtin_amdgcn_mfma_f32_16x16x32_bf16(av[f], bv[b2], acc[f][b2], 0, 0, 0);
    __builtin_amdgcn_s_setprio(0);
    __builtin_amdgcn_s_barrier();
    // ---- phase 1: (fh=1, kh=0) ----
    RD_A(t, 0, 1, av);
    if (t + 1 < NT) STAGE(gB, t + 1, 1, 1);
    if (t >= NT - 2) asm volatile("s_waitcnt vmcnt(0)" ::: "memory");
    else             asm volatile("s_waitcnt vmcnt(8)" ::: "memory");
    __builtin_amdgcn_s_barrier();
    asm volatile("s_waitcnt lgkmcnt(0)" ::: "memory");
    __builtin_amdgcn_s_setprio(1);
#pragma unroll
    for (int f = 0; f < 4; ++f)
#pragma unroll
      for (int b2 = 0; b2 < 4; ++b2)
        acc[4 + f][b2] = __builtin_amdgcn_mfma_f32_16x16x32_bf16(av[f], bv[b2], acc[4 + f][b2], 0, 0, 0);
    __builtin_amdgcn_s_setprio(0);
    __builtin_amdgcn_s_barrier();
    // ---- phase 2: (fh=0, kh=1) ----
    RD_A(t, 1, 0, av); RD_B(t, 1, bv);
    if (t + 2 < NT) STAGE(gA, t + 2, 0, 0);
    __builtin_amdgcn_s_barrier();
    asm volatile("s_waitcnt lgkmcnt(0)" ::: "memory");
    __builtin_amdgcn_s_setprio(1);
#pragma unroll
    for (int f = 0; f < 4; ++f)
#pragma unroll
      for (int b2 = 0; b2 < 4; ++b2)
        acc[f][b2] = __builtin_amdgcn_mfma_f32_16x16x32_bf16(av[f], bv[b2], acc[f][b2], 0, 0, 0);
    __builtin_amdgcn_s_setprio(0);
    __builtin_amdgcn_s_barrier();
    // ---- phase 3: (fh=1, kh=1) ----
    RD_A(t, 1, 1, av);
    if (t + 2 < NT) STAGE(gB, t + 2, 0, 1);
    if (t >= NT - 2) asm volatile("s_waitcnt vmcnt(0)" ::: "memory");
    else             asm volatile("s_waitcnt vmcnt(8)" ::: "memory");
    __builtin_amdgcn_s_barrier();
    asm volatile("s_waitcnt lgkmcnt(0)" ::: "memory");
    __builtin_amdgcn_s_setprio(1);
#pragma unroll
    for (int f = 0; f < 4; ++f)
#pragma unroll
      for (int b2 = 0; b2 < 4; ++b2)
        acc[4 + f][b2] = __builtin_amdgcn_mfma_f32_16x16x32_bf16(av[f], bv[b2], acc[4 + f][b2], 0, 0, 0);
    __builtin_amdgcn_s_setprio(0);
    __builtin_amdgcn_s_barrier();
  }

#pragma unroll
  for (int fa = 0; fa < 8; ++fa)
#pragma unroll
    for (int fb = 0; fb < 4; ++fb)
#pragma unroll
      for (int j = 0; j < 4; ++j) {
        long grow = rowBase + wm * 128 + fa * 16 + hi * 4 + j;
        long gcol = colBase + wn * 64 + fb * 16 + l15;
        float v = acc[fa][fb][j];
        if (EPI == 0) {
          C[grow * DM + gcol] = v;
        } else if (EPI == 1) {
          if (gcol < DM) {
            float t = v * w0[gcol] + w1[gcol];
            o0[grow * DM + gcol] = f2bf(t / (1.f + __expf(-t)));
          } else {
            o1[grow * DM + (gcol - DM)] = f2bf(v / (1.f + __expf(-v)));
          }
        } else {
          float t = v + w0[gcol];
          float d = (t > 20.f) ? t : log1pf(__expf(t));
          o0[grow * DM + gcol] = f2bf(d);
        }
      }
}

// ---------------- Bm/C: dots of xc with x_proj_w rows 48,49 (fp32 weights) ----------------
__global__ __launch_bounds__(256)
void bmc_k(const u16* __restrict__ xcb, const float* __restrict__ xw,
           float* __restrict__ bmc) {
  int lane = threadIdx.x & 63, wid = threadIdx.x >> 6;
  long t = (long)blockIdx.x * 4 + wid;
  const u16* xr = xcb + t * DM;
  const float* w48 = xw + 48 * DM;
  const float* w49 = xw + 49 * DM;
  float s0 = 0.f, s1 = 0.f;
#pragma unroll
  for (int i = 0; i < 3; ++i) {
    int e = i * 256 + lane * 4;
    ushort4 xv = *(const ushort4*)&xr[e];
    float4 a = *(const float4*)&w48[e];
    float4 b = *(const float4*)&w49[e];
    float x0 = bf2f(xv.x), x1 = bf2f(xv.y), x2 = bf2f(xv.z), x3 = bf2f(xv.w);
    s0 += x0 * a.x + x1 * a.y + x2 * a.z + x3 * a.w;
    s1 += x0 * b.x + x1 * b.y + x2 * b.z + x3 * b.w;
  }
#pragma unroll
  for (int o = 32; o; o >>= 1) { s0 += __shfl_down(s0, o, 64); s1 += __shfl_down(s1, o, 64); }
  if (lane == 0) { bmc[t * 2] = s0; bmc[t * 2 + 1] = s1; }
}

// ---------------- selective scan (N_STATE=1), chunked 3-pass, 2 channels/thread ----
__global__ __launch_bounds__(384)
void scan1_k(const u16* __restrict__ deltab, const u16* __restrict__ xcb,
             const float* __restrict__ bmc, const float* __restrict__ A_log,
             float* __restrict__ aprod, float* __restrict__ hend) {
  int pe = threadIdx.x;          // 0..383 (channel pair)
  int b = blockIdx.x, c = blockIdx.y;
  int e0 = pe * 2;
  float Ae0 = -__expf(A_log[e0]), Ae1 = -__expf(A_log[e0 + 1]);
  float ap0 = 1.f, h0 = 0.f, ap1 = 1.f, h1 = 0.f;
  long base = (long)b * LSEQ + (long)c * CL;
  for (int i = 0; i < CL; ++i) {
    long t = base + i;
    u32 dv = *(const u32*)&deltab[t * DM + e0];
    u32 xv = *(const u32*)&xcb[t * DM + e0];
    float Bm = bmc[t * 2];
    float d0 = bf2f(dv), d1 = bf2f(dv >> 16);
    float x0 = bf2f(xv), x1 = bf2f(xv >> 16);
    float a0 = __expf(d0 * Ae0), a1 = __expf(d1 * Ae1);
    ap0 *= a0; h0 = a0 * h0 + d0 * Bm * x0;
    ap1 *= a1; h1 = a1 * h1 + d1 * Bm * x1;
  }
  long chain = (long)c * NCHAIN + b * DM + e0;
  *(float2*)&aprod[chain] = make_float2(ap0, ap1);
  *(float2*)&hend[chain]  = make_float2(h0, h1);
}

__global__ __launch_bounds__(256)
void scan2_k(const float* __restrict__ aprod, const float* __restrict__ hend,
             float* __restrict__ carry) {
  int chain = blockIdx.x * 256 + threadIdx.x;
  float h = 0.f;
  for (int c = 0; c < NC; ++c) {
    carry[c * NCHAIN + chain] = h;
    h = aprod[c * NCHAIN + chain] * h + hend[c * NCHAIN + chain];
  }
}

__global__ __launch_bounds__(384)
void scan3_k(const u16* __restrict__ deltab, const u16* __restrict__ xcb,
             const float* __restrict__ bmc, const float* __restrict__ A_log,
             const float* __restrict__ Dp, const u16* __restrict__ szb,
             const float* __restrict__ carry, u16* __restrict__ ybf) {
  int pe = threadIdx.x;
  int b = blockIdx.x, c = blockIdx.y;
  int e0 = pe * 2;
  float Ae0 = -__expf(A_log[e0]), Ae1 = -__expf(A_log[e0 + 1]);
  float De0 = Dp[e0], De1 = Dp[e0 + 1];
  long chain = (long)c * NCHAIN + b * DM + e0;
  float2 hc = *(const float2*)&carry[chain];
  float h0 = hc.x, h1 = hc.y;
  long base = (long)b * LSEQ + (long)c * CL;
  for (int i = 0; i < CL; ++i) {
    long t = base + i;
    u32 dv = *(const u32*)&deltab[t * DM + e0];
    u32 xv = *(const u32*)&xcb[t * DM + e0];
    u32 sv = *(const u32*)&szb[t * DM + e0];
    float Bm = bmc[t * 2], Cc = bmc[t * 2 + 1];
    float d0 = bf2f(dv), d1 = bf2f(dv >> 16);
    float x0 = bf2f(xv), x1 = bf2f(xv >> 16);
    float a0 = __expf(d0 * Ae0), a1 = __expf(d1 * Ae1);
    h0 = a0 * h0 + d0 * Bm * x0;
    h1 = a1 * h1 + d1 * Bm * x1;
    float y0 = (h0 * Cc + De0 * x0) * bf2f(sv);
    float y1 = (h1 * Cc + De1 * x1) * bf2f(sv >> 16);
    *(u32*)&ybf[t * DM + e0] = (u32)f2bf(y0) | ((u32)f2bf(y1) << 16);
  }
}

// ---------------- launch ----------------
extern "C" void kernel_launch(void* const* d_in, const int* in_sizes, int n_in,
                              void* d_out, int out_size, void* d_ws, size_t ws_size,
                              hipStream_t stream) {
  const float* x         = (const float*)d_in[0];
  const float* rms_w     = (const float*)d_in[1];
  const float* in_proj_w = (const float*)d_in[2];
  const float* conv_w    = (const float*)d_in[3];
  const float* conv_b    = (const float*)d_in[4];
  const float* x_proj_w  = (const float*)d_in[5];
  const float* dt_proj_w = (const float*)d_in[6];
  const float* dt_proj_b = (const float*)d_in[7];
  const float* A_log     = (const float*)d_in[8];
  const float* Dp        = (const float*)d_in[9];
  const float* out_proj_w= (const float*)d_in[10];
  float* out = (float*)d_out;

  char* ws = (char*)d_ws;
  size_t off = 0;
  auto alloc = [&](size_t bytes) -> void* {
    void* p = ws + off;
    off += (bytes + 255) & ~(size_t)255;
    return p;
  };
  u16*   xnb    = (u16*)alloc((size_t)TOK * DM * 2);
  u16*   xcb    = (u16*)alloc((size_t)TOK * DM * 2);
  u16*   szb    = (u16*)alloc((size_t)TOK * DM * 2);
  u16*   ybf    = (u16*)alloc((size_t)TOK * DM * 2);
  u16*   deltab = (u16*)alloc((size_t)TOK * DM * 2);
  float* bmc    = (float*)alloc((size_t)TOK * 2 * 4);
  u16*   wInB   = (u16*)alloc((size_t)1536 * 768 * 2);
  u16*   wDtB   = (u16*)alloc((size_t)768 * 768 * 2);
  u16*   wOutB  = (u16*)alloc((size_t)768 * 768 * 2);
  float* aprod  = (float*)alloc((size_t)NC * NCHAIN * 4);
  float* hend   = (float*)alloc((size_t)NC * NCHAIN * 4);
  float* carry  = (float*)alloc((size_t)NC * NCHAIN * 4);

  cvt_k<<<(1536 * 768 + 255) / 256, 256, 0, stream>>>(in_proj_w, wInB, 1536 * 768);
  cvt_k<<<(768 * 768 + 255) / 256, 256, 0, stream>>>(out_proj_w, wOutB, 768 * 768);
  wdt_k<<<768, 256, 0, stream>>>(dt_proj_w, x_proj_w, wDtB);

  rmsnorm_k<<<TOK, 192, 0, stream>>>(x, rms_w, xnb);

  // xz = xn @ in_proj_w^T ; fused conv+silu -> xcb, silu(z) -> szb
  gemm256<1><<<dim3(1536 / 256, TOK / 256), 512, 0, stream>>>(
      xnb, wInB, nullptr, conv_w, conv_b, xcb, szb);

  // Bm/C via fp32 dots
  bmc_k<<<TOK / 4, 256, 0, stream>>>(xcb, x_proj_w, bmc);

  // delta = softplus(xc @ W_dt^T + dt_b) -> bf16
  gemm256<2><<<dim3(768 / 256, TOK / 256), 512, 0, stream>>>(
      xcb, wDtB, nullptr, dt_proj_b, nullptr, deltab, nullptr);

  scan1_k<<<dim3(8, NC), 384, 0, stream>>>(deltab, xcb, bmc, A_log, aprod, hend);
  scan2_k<<<NCHAIN / 256, 256, 0, stream>>>(aprod, hend, carry);
  scan3_k<<<dim3(8, NC), 384, 0, stream>>>(deltab, xcb, bmc, A_log, Dp, szb, carry, ybf);

  // out = (y * silu(z)) @ out_proj_w^T
  gemm256<0><<<dim3(768 / 256, TOK / 256), 512, 0, stream>>>(
      ybf, wOutB, out, nullptr, nullptr, nullptr, nullptr);
}

// Round 4
// 561.502 us; speedup vs baseline: 1.5055x; 1.5055x over previous
//
#include <hip/hip_runtime.h>

#define TOK   32768
#define DM    768
#define KDIM  768
#define LSEQ  4096
#define NC    64
#define CL    64
#define NCHAIN 6144

typedef __bf16 bf16x8 __attribute__((ext_vector_type(8)));
typedef float  f32x4  __attribute__((ext_vector_type(4)));
typedef unsigned short u16;
typedef unsigned int u32;

__device__ __forceinline__ u16 f2bf(float f) {
  unsigned u = __builtin_bit_cast(unsigned, f);
  u += 0x7fffu + ((u >> 16) & 1u);
  return (u16)(u >> 16);
}
__device__ __forceinline__ float bf2f(u32 h) {
  unsigned u = (h & 0xffffu) << 16;
  return __builtin_bit_cast(float, u);
}

#define GLOAD_LDS16(g, l) __builtin_amdgcn_global_load_lds( \
    (const __attribute__((address_space(1))) void*)(g),     \
    (__attribute__((address_space(3))) void*)(l), 16, 0, 0)

// ---------------- fp32 -> bf16 weight convert ----------------
__global__ void cvt_k(const float* __restrict__ src, u16* __restrict__ dst, int n) {
  int i = blockIdx.x * 256 + threadIdx.x;
  if (i < n) dst[i] = f2bf(src[i]);
}

// ---------------- W_dt = dt_proj_w (768x48) @ x_proj_w[:48] (48x768) -> bf16 ----------------
__global__ __launch_bounds__(256)
void wdt_k(const float* __restrict__ dtw, const float* __restrict__ xw,
           u16* __restrict__ W) {
  int i = blockIdx.x;
  int j = threadIdx.x;
  float a0 = 0.f, a1 = 0.f, a2 = 0.f;
  for (int r = 0; r < 48; ++r) {
    float d = dtw[i * 48 + r];
    const float* xr = xw + r * DM;
    a0 += d * xr[j];
    a1 += d * xr[j + 256];
    a2 += d * xr[j + 512];
  }
  W[i * DM + j]       = f2bf(a0);
  W[i * DM + j + 256] = f2bf(a1);
  W[i * DM + j + 512] = f2bf(a2);
}

// ---------------- RMSNorm: x (fp32) -> xn (bf16), float4 path ----------------
__global__ __launch_bounds__(192)
void rmsnorm_k(const float* __restrict__ x, const float* __restrict__ w,
               u16* __restrict__ xnb) {
  long t = blockIdx.x;
  int tid = threadIdx.x;
  float4 v = ((const float4*)x)[t * 192 + tid];
  float s = v.x * v.x + v.y * v.y + v.z * v.z + v.w * v.w;
#pragma unroll
  for (int o = 32; o; o >>= 1) s += __shfl_down(s, o, 64);
  __shared__ float red[3];
  if ((tid & 63) == 0) red[tid >> 6] = s;
  __syncthreads();
  float sc = rsqrtf((red[0] + red[1] + red[2]) * (1.f / 768.f) + 1e-6f);
  float4 ww = ((const float4*)w)[tid];
  ushort4 o;
  o.x = f2bf(v.x * sc * ww.x);
  o.y = f2bf(v.y * sc * ww.y);
  o.z = f2bf(v.z * sc * ww.z);
  o.w = f2bf(v.w * sc * ww.w);
  ((ushort4*)xnb)[t * 192 + tid] = o;
}

// ---------------- MFMA GEMM (round-1 structure + conflict-free LDS swizzle) ----
// C[m][n] = sum_k A[m][k]*B[n][k]; A,B bf16 row-major, stride KDIM=768, K=768.
// BM=BN=128, BK=32, 256 threads = 4 waves (2x2), each wave 64x64 (4x4 frags).
// Tile row = 64B = 4 x 16B slots; phys slot = logical ^ ((row>>1)&3), applied on
// the per-lane GLOBAL source address (gload_lds writes LDS linearly) and on the
// ds_read address (rule 21: both sides, same involution). Spreads the old 8-way
// ds_read_b128 conflict across 8 banks -> 2-way (free).
// EPI: 0 fp32 C; 1 in_proj (conv+silu->o0, silu(z)->o1); 2 bias+softplus->o0 bf16.
template <int EPI>
__global__ __launch_bounds__(256)
void gemm_bt(const u16* __restrict__ A, const u16* __restrict__ B,
             float* __restrict__ C,
             const float* __restrict__ w0, const float* __restrict__ w1,
             u16* __restrict__ o0, u16* __restrict__ o1) {
  __shared__ __align__(16) u16 smA[128 * 32];
  __shared__ __align__(16) u16 smB[128 * 32];
  const int tid = threadIdx.x;
  const int lane = tid & 63;
  const int wid = tid >> 6;
  const long rowBase = (long)blockIdx.y * 128;
  const long colBase = (long)blockIdx.x * 128;

  const int wr = (wid >> 1) * 64;
  const int wc = (wid & 1) * 64;
  const int lr = lane & 15;
  const int kc = lane >> 4;
  const int kcs = kc ^ ((lr >> 1) & 3);   // swizzled 16B slot for ds_read

  // staging source (pre-swizzled): chunk c -> row c>>2, logical slot (c&3)^((c>>3)&3)
  const int c1 = tid + 256;
  const u16* gA0 = A + (rowBase + (tid >> 2)) * KDIM + ((tid & 3) ^ ((tid >> 3) & 3)) * 8;
  const u16* gA1 = A + (rowBase + (c1 >> 2)) * KDIM + ((c1 & 3) ^ ((c1 >> 3) & 3)) * 8;
  const u16* gB0 = B + (colBase + (tid >> 2)) * KDIM + ((tid & 3) ^ ((tid >> 3) & 3)) * 8;
  const u16* gB1 = B + (colBase + (c1 >> 2)) * KDIM + ((c1 & 3) ^ ((c1 >> 3) & 3)) * 8;

  f32x4 acc[4][4] = {};

  for (int kt = 0; kt < KDIM; kt += 32) {
    GLOAD_LDS16(gA0 + kt, &smA[tid * 8]);
    GLOAD_LDS16(gA1 + kt, &smA[c1 * 8]);
    GLOAD_LDS16(gB0 + kt, &smB[tid * 8]);
    GLOAD_LDS16(gB1 + kt, &smB[c1 * 8]);
    __syncthreads();
    bf16x8 af[4], bfr[4];
#pragma unroll
    for (int m = 0; m < 4; ++m)
      af[m] = *(const bf16x8*)&smA[(wr + m * 16 + lr) * 32 + kcs * 8];
#pragma unroll
    for (int n = 0; n < 4; ++n)
      bfr[n] = *(const bf16x8*)&smB[(wc + n * 16 + lr) * 32 + kcs * 8];
#pragma unroll
    for (int m = 0; m < 4; ++m)
#pragma unroll
      for (int n = 0; n < 4; ++n)
        acc[m][n] = __builtin_amdgcn_mfma_f32_16x16x32_bf16(af[m], bfr[n], acc[m][n], 0, 0, 0);
    __syncthreads();
  }

#pragma unroll
  for (int m = 0; m < 4; ++m)
#pragma unroll
    for (int n = 0; n < 4; ++n)
#pragma unroll
      for (int j = 0; j < 4; ++j) {
        long grow = rowBase + wr + m * 16 + kc * 4 + j;
        long gcol = colBase + wc + n * 16 + lr;
        float v = acc[m][n][j];
        if (EPI == 0) {
          C[grow * DM + gcol] = v;
        } else if (EPI == 1) {
          if (gcol < DM) {
            float t = v * w0[gcol] + w1[gcol];
            o0[grow * DM + gcol] = f2bf(t / (1.f + __expf(-t)));
          } else {
            o1[grow * DM + (gcol - DM)] = f2bf(v / (1.f + __expf(-v)));
          }
        } else {
          float t = v + w0[gcol];
          float d = (t > 20.f) ? t : log1pf(__expf(t));
          o0[grow * DM + gcol] = f2bf(d);
        }
      }
}

// ---------------- Bm/C: dots of xc with x_proj_w rows 48,49 (fp32 weights) ----------------
__global__ __launch_bounds__(256)
void bmc_k(const u16* __restrict__ xcb, const float* __restrict__ xw,
           float* __restrict__ bmc) {
  int lane = threadIdx.x & 63, wid = threadIdx.x >> 6;
  long t = (long)blockIdx.x * 4 + wid;
  const u16* xr = xcb + t * DM;
  const float* w48 = xw + 48 * DM;
  const float* w49 = xw + 49 * DM;
  float s0 = 0.f, s1 = 0.f;
#pragma unroll
  for (int i = 0; i < 3; ++i) {
    int e = i * 256 + lane * 4;
    ushort4 xv = *(const ushort4*)&xr[e];
    float4 a = *(const float4*)&w48[e];
    float4 b = *(const float4*)&w49[e];
    float x0 = bf2f(xv.x), x1 = bf2f(xv.y), x2 = bf2f(xv.z), x3 = bf2f(xv.w);
    s0 += x0 * a.x + x1 * a.y + x2 * a.z + x3 * a.w;
    s1 += x0 * b.x + x1 * b.y + x2 * b.z + x3 * b.w;
  }
#pragma unroll
  for (int o = 32; o; o >>= 1) { s0 += __shfl_down(s0, o, 64); s1 += __shfl_down(s1, o, 64); }
  if (lane == 0) { bmc[t * 2] = s0; bmc[t * 2 + 1] = s1; }
}

// ---------------- selective scan (N_STATE=1), chunked 3-pass, 2 channels/thread ----
__global__ __launch_bounds__(384)
void scan1_k(const u16* __restrict__ deltab, const u16* __restrict__ xcb,
             const float* __restrict__ bmc, const float* __restrict__ A_log,
             float* __restrict__ aprod, float* __restrict__ hend) {
  int pe = threadIdx.x;
  int b = blockIdx.x, c = blockIdx.y;
  int e0 = pe * 2;
  float Ae0 = -__expf(A_log[e0]), Ae1 = -__expf(A_log[e0 + 1]);
  float ap0 = 1.f, h0 = 0.f, ap1 = 1.f, h1 = 0.f;
  long base = (long)b * LSEQ + (long)c * CL;
  for (int i = 0; i < CL; ++i) {
    long t = base + i;
    u32 dv = *(const u32*)&deltab[t * DM + e0];
    u32 xv = *(const u32*)&xcb[t * DM + e0];
    float Bm = bmc[t * 2];
    float d0 = bf2f(dv), d1 = bf2f(dv >> 16);
    float x0 = bf2f(xv), x1 = bf2f(xv >> 16);
    float a0 = __expf(d0 * Ae0), a1 = __expf(d1 * Ae1);
    ap0 *= a0; h0 = a0 * h0 + d0 * Bm * x0;
    ap1 *= a1; h1 = a1 * h1 + d1 * Bm * x1;
  }
  long chain = (long)c * NCHAIN + b * DM + e0;
  *(float2*)&aprod[chain] = make_float2(ap0, ap1);
  *(float2*)&hend[chain]  = make_float2(h0, h1);
}

__global__ __launch_bounds__(256)
void scan2_k(const float* __restrict__ aprod, const float* __restrict__ hend,
             float* __restrict__ carry) {
  int chain = blockIdx.x * 256 + threadIdx.x;
  float h = 0.f;
  for (int c = 0; c < NC; ++c) {
    carry[c * NCHAIN + chain] = h;
    h = aprod[c * NCHAIN + chain] * h + hend[c * NCHAIN + chain];
  }
}

__global__ __launch_bounds__(384)
void scan3_k(const u16* __restrict__ deltab, const u16* __restrict__ xcb,
             const float* __restrict__ bmc, const float* __restrict__ A_log,
             const float* __restrict__ Dp, const u16* __restrict__ szb,
             const float* __restrict__ carry, u16* __restrict__ ybf) {
  int pe = threadIdx.x;
  int b = blockIdx.x, c = blockIdx.y;
  int e0 = pe * 2;
  float Ae0 = -__expf(A_log[e0]), Ae1 = -__expf(A_log[e0 + 1]);
  float De0 = Dp[e0], De1 = Dp[e0 + 1];
  long chain = (long)c * NCHAIN + b * DM + e0;
  float2 hc = *(const float2*)&carry[chain];
  float h0 = hc.x, h1 = hc.y;
  long base = (long)b * LSEQ + (long)c * CL;
  for (int i = 0; i < CL; ++i) {
    long t = base + i;
    u32 dv = *(const u32*)&deltab[t * DM + e0];
    u32 xv = *(const u32*)&xcb[t * DM + e0];
    u32 sv = *(const u32*)&szb[t * DM + e0];
    float Bm = bmc[t * 2], Cc = bmc[t * 2 + 1];
    float d0 = bf2f(dv), d1 = bf2f(dv >> 16);
    float x0 = bf2f(xv), x1 = bf2f(xv >> 16);
    float a0 = __expf(d0 * Ae0), a1 = __expf(d1 * Ae1);
    h0 = a0 * h0 + d0 * Bm * x0;
    h1 = a1 * h1 + d1 * Bm * x1;
    float y0 = (h0 * Cc + De0 * x0) * bf2f(sv);
    float y1 = (h1 * Cc + De1 * x1) * bf2f(sv >> 16);
    *(u32*)&ybf[t * DM + e0] = (u32)f2bf(y0) | ((u32)f2bf(y1) << 16);
  }
}

// ---------------- launch ----------------
extern "C" void kernel_launch(void* const* d_in, const int* in_sizes, int n_in,
                              void* d_out, int out_size, void* d_ws, size_t ws_size,
                              hipStream_t stream) {
  const float* x         = (const float*)d_in[0];
  const float* rms_w     = (const float*)d_in[1];
  const float* in_proj_w = (const float*)d_in[2];
  const float* conv_w    = (const float*)d_in[3];
  const float* conv_b    = (const float*)d_in[4];
  const float* x_proj_w  = (const float*)d_in[5];
  const float* dt_proj_w = (const float*)d_in[6];
  const float* dt_proj_b = (const float*)d_in[7];
  const float* A_log     = (const float*)d_in[8];
  const float* Dp        = (const float*)d_in[9];
  const float* out_proj_w= (const float*)d_in[10];
  float* out = (float*)d_out;

  char* ws = (char*)d_ws;
  size_t off = 0;
  auto alloc = [&](size_t bytes) -> void* {
    void* p = ws + off;
    off += (bytes + 255) & ~(size_t)255;
    return p;
  };
  u16*   xnb    = (u16*)alloc((size_t)TOK * DM * 2);
  u16*   xcb    = (u16*)alloc((size_t)TOK * DM * 2);
  u16*   szb    = (u16*)alloc((size_t)TOK * DM * 2);
  u16*   ybf    = (u16*)alloc((size_t)TOK * DM * 2);
  u16*   deltab = (u16*)alloc((size_t)TOK * DM * 2);
  float* bmc    = (float*)alloc((size_t)TOK * 2 * 4);
  u16*   wInB   = (u16*)alloc((size_t)1536 * 768 * 2);
  u16*   wDtB   = (u16*)alloc((size_t)768 * 768 * 2);
  u16*   wOutB  = (u16*)alloc((size_t)768 * 768 * 2);
  float* aprod  = (float*)alloc((size_t)NC * NCHAIN * 4);
  float* hend   = (float*)alloc((size_t)NC * NCHAIN * 4);
  float* carry  = (float*)alloc((size_t)NC * NCHAIN * 4);

  cvt_k<<<(1536 * 768 + 255) / 256, 256, 0, stream>>>(in_proj_w, wInB, 1536 * 768);
  cvt_k<<<(768 * 768 + 255) / 256, 256, 0, stream>>>(out_proj_w, wOutB, 768 * 768);
  wdt_k<<<768, 256, 0, stream>>>(dt_proj_w, x_proj_w, wDtB);

  rmsnorm_k<<<TOK, 192, 0, stream>>>(x, rms_w, xnb);

  // xz = xn @ in_proj_w^T ; fused conv+silu -> xcb, silu(z) -> szb
  gemm_bt<1><<<dim3(1536 / 128, TOK / 128), 256, 0, stream>>>(
      xnb, wInB, nullptr, conv_w, conv_b, xcb, szb);

  // Bm/C via fp32 dots
  bmc_k<<<TOK / 4, 256, 0, stream>>>(xcb, x_proj_w, bmc);

  // delta = softplus(xc @ W_dt^T + dt_b) -> bf16
  gemm_bt<2><<<dim3(768 / 128, TOK / 128), 256, 0, stream>>>(
      xcb, wDtB, nullptr, dt_proj_b, nullptr, deltab, nullptr);

  scan1_k<<<dim3(8, NC), 384, 0, stream>>>(deltab, xcb, bmc, A_log, aprod, hend);
  scan2_k<<<NCHAIN / 256, 256, 0, stream>>>(aprod, hend, carry);
  scan3_k<<<dim3(8, NC), 384, 0, stream>>>(deltab, xcb, bmc, A_log, Dp, szb, carry, ybf);

  // out = (y * silu(z)) @ out_proj_w^T
  gemm_bt<0><<<dim3(768 / 128, TOK / 128), 256, 0, stream>>>(
      ybf, wOutB, out, nullptr, nullptr, nullptr, nullptr);
}

// Round 5
// 381.843 us; speedup vs baseline: 2.2139x; 1.4705x over previous
//
#include <hip/hip_runtime.h>

#define TOK   32768
#define DM    768
#define KDIM  768
#define LSEQ  4096
#define NC    64
#define CL    64
#define NCHAIN 6144

typedef __bf16 bf16x8 __attribute__((ext_vector_type(8)));
typedef float  f32x4  __attribute__((ext_vector_type(4)));
typedef unsigned short u16;
typedef unsigned int u32;

__device__ __forceinline__ u16 f2bf(float f) {
  unsigned u = __builtin_bit_cast(unsigned, f);
  u += 0x7fffu + ((u >> 16) & 1u);
  return (u16)(u >> 16);
}
__device__ __forceinline__ float bf2f(u32 h) {
  unsigned u = (h & 0xffffu) << 16;
  return __builtin_bit_cast(float, u);
}

#define GLOAD_LDS16(g, l) __builtin_amdgcn_global_load_lds( \
    (const __attribute__((address_space(1))) void*)(g),     \
    (__attribute__((address_space(3))) void*)(l), 16, 0, 0)

// ---------------- fp32 -> bf16 weight convert ----------------
__global__ void cvt_k(const float* __restrict__ src, u16* __restrict__ dst, int n) {
  int i = blockIdx.x * 256 + threadIdx.x;
  if (i < n) dst[i] = f2bf(src[i]);
}

// ---------------- fp32 -> bf16 with zero padding ----------------
__global__ void cvt_pad_k(const float* __restrict__ src, u16* __restrict__ dst,
                          int rows, int cols, int dcols, int n) {
  int i = blockIdx.x * 256 + threadIdx.x;
  if (i >= n) return;
  int r = i / dcols, c = i % dcols;
  dst[i] = (r < rows && c < cols) ? f2bf(src[r * cols + c]) : (u16)0;
}

// ---------------- RMSNorm: x (fp32) -> xn (bf16), float4 path ----------------
__global__ __launch_bounds__(192)
void rmsnorm_k(const float* __restrict__ x, const float* __restrict__ w,
               u16* __restrict__ xnb) {
  long t = blockIdx.x;
  int tid = threadIdx.x;
  float4 v = ((const float4*)x)[t * 192 + tid];
  float s = v.x * v.x + v.y * v.y + v.z * v.z + v.w * v.w;
#pragma unroll
  for (int o = 32; o; o >>= 1) s += __shfl_down(s, o, 64);
  __shared__ float red[3];
  if ((tid & 63) == 0) red[tid >> 6] = s;
  __syncthreads();
  float sc = rsqrtf((red[0] + red[1] + red[2]) * (1.f / 768.f) + 1e-6f);
  float4 ww = ((const float4*)w)[tid];
  ushort4 o;
  o.x = f2bf(v.x * sc * ww.x);
  o.y = f2bf(v.y * sc * ww.y);
  o.z = f2bf(v.z * sc * ww.z);
  o.w = f2bf(v.w * sc * ww.w);
  ((ushort4*)xnb)[t * 192 + tid] = o;
}

// ---------------- BK=64 MFMA GEMM (in_proj / out_proj), K = 768 ----------------
// C[m][n] = sum_k A[m][k]*B[n][k]; A,B bf16 row-major stride KDIM. BM=BN=128.
// 256 thr = 4 waves (2x2), wave = 64x64 (4x4 frags). 12 K-steps of 64.
// Tile row = 128B = 8 x 16B slots; phys slot = logical ^ (row&7), applied on the
// per-lane GLOBAL source (gload_lds writes LDS linearly) and on ds_read (rule 21).
// EPI: 0 fp32 C store; 1 in_proj (conv+silu->o0, silu(z)->o1).
template <int EPI>
__global__ __launch_bounds__(256)
void gemm64(const u16* __restrict__ A, const u16* __restrict__ B,
            float* __restrict__ C,
            const float* __restrict__ w0, const float* __restrict__ w1,
            u16* __restrict__ o0, u16* __restrict__ o1) {
  __shared__ __align__(16) u16 smA[128 * 64];
  __shared__ __align__(16) u16 smB[128 * 64];
  const int tid = threadIdx.x;
  const int lane = tid & 63;
  const int wid = tid >> 6;
  const long rowBase = (long)blockIdx.y * 128;
  const long colBase = (long)blockIdx.x * 128;

  const int wr = (wid >> 1) * 64;
  const int wc = (wid & 1) * 64;
  const int lr = lane & 15;
  const int kc = lane >> 4;

  // staging: 1024 chunks of 16B per matrix; thread owns cc = tid + i*256, i<4.
  // row = cc>>3, phys slot = cc&7, logical slot = (cc&7)^((cc>>3)&7).
  const u16* gA[4];
  const u16* gB[4];
#pragma unroll
  for (int i = 0; i < 4; ++i) {
    int cc = tid + i * 256;
    int row = cc >> 3;
    int lg = (cc & 7) ^ (row & 7);
    gA[i] = A + (rowBase + row) * KDIM + lg * 8;
    gB[i] = B + (colBase + row) * KDIM + lg * 8;
  }

  f32x4 acc[4][4] = {};

  for (int kt = 0; kt < KDIM; kt += 64) {
#pragma unroll
    for (int i = 0; i < 4; ++i) {
      GLOAD_LDS16(gA[i] + kt, &smA[(tid + i * 256) * 8]);
      GLOAD_LDS16(gB[i] + kt, &smB[(tid + i * 256) * 8]);
    }
    __syncthreads();
#pragma unroll
    for (int kh = 0; kh < 2; ++kh) {
      const int ps = (kc + 4 * kh) ^ (lr & 7);
      bf16x8 af[4], bfr[4];
#pragma unroll
      for (int m = 0; m < 4; ++m)
        af[m] = *(const bf16x8*)&smA[(wr + m * 16 + lr) * 64 + ps * 8];
#pragma unroll
      for (int n = 0; n < 4; ++n)
        bfr[n] = *(const bf16x8*)&smB[(wc + n * 16 + lr) * 64 + ps * 8];
#pragma unroll
      for (int m = 0; m < 4; ++m)
#pragma unroll
        for (int n = 0; n < 4; ++n)
          acc[m][n] = __builtin_amdgcn_mfma_f32_16x16x32_bf16(af[m], bfr[n], acc[m][n], 0, 0, 0);
    }
    __syncthreads();
  }

#pragma unroll
  for (int m = 0; m < 4; ++m)
#pragma unroll
    for (int n = 0; n < 4; ++n)
#pragma unroll
      for (int j = 0; j < 4; ++j) {
        long grow = rowBase + wr + m * 16 + kc * 4 + j;
        long gcol = colBase + wc + n * 16 + lr;
        float v = acc[m][n][j];
        if (EPI == 0) {
          C[grow * DM + gcol] = v;
        } else {
          if (gcol < DM) {
            float t = v * w0[gcol] + w1[gcol];
            o0[grow * DM + gcol] = f2bf(t / (1.f + __expf(-t)));
          } else {
            o1[grow * DM + (gcol - DM)] = f2bf(v / (1.f + __expf(-v)));
          }
        }
      }
}

// ---------------- BK=32 MFMA GEMM (x_proj / dt_proj), generic lda/ldb/K ----------
// EPI: 2 dt_proj (bias + fast softplus -> o0 bf16, stride DM);
//      3 x_proj (cols<64 -> o0 bf16 stride 64; cols 48/49 -> C fp32 at t*2+{0,1}).
template <int EPI>
__global__ __launch_bounds__(256)
void gemm_bt(const u16* __restrict__ A, int lda,
             const u16* __restrict__ B, int ldb, int K,
             float* __restrict__ C,
             const float* __restrict__ w0,
             u16* __restrict__ o0) {
  __shared__ __align__(16) u16 smA[128 * 32];
  __shared__ __align__(16) u16 smB[128 * 32];
  const int tid = threadIdx.x;
  const int lane = tid & 63;
  const int wid = tid >> 6;
  const long rowBase = (long)blockIdx.y * 128;
  const long colBase = (long)blockIdx.x * 128;

  const int wr = (wid >> 1) * 64;
  const int wc = (wid & 1) * 64;
  const int lr = lane & 15;
  const int kc = lane >> 4;
  const int kcs = kc ^ ((lr >> 1) & 3);

  const int c1 = tid + 256;
  const u16* gA0 = A + (rowBase + (tid >> 2)) * lda + ((tid & 3) ^ ((tid >> 3) & 3)) * 8;
  const u16* gA1 = A + (rowBase + (c1 >> 2)) * lda + ((c1 & 3) ^ ((c1 >> 3) & 3)) * 8;
  const u16* gB0 = B + (colBase + (tid >> 2)) * ldb + ((tid & 3) ^ ((tid >> 3) & 3)) * 8;
  const u16* gB1 = B + (colBase + (c1 >> 2)) * ldb + ((c1 & 3) ^ ((c1 >> 3) & 3)) * 8;

  f32x4 acc[4][4] = {};

  for (int kt = 0; kt < K; kt += 32) {
    GLOAD_LDS16(gA0 + kt, &smA[tid * 8]);
    GLOAD_LDS16(gA1 + kt, &smA[c1 * 8]);
    GLOAD_LDS16(gB0 + kt, &smB[tid * 8]);
    GLOAD_LDS16(gB1 + kt, &smB[c1 * 8]);
    __syncthreads();
    bf16x8 af[4], bfr[4];
#pragma unroll
    for (int m = 0; m < 4; ++m)
      af[m] = *(const bf16x8*)&smA[(wr + m * 16 + lr) * 32 + kcs * 8];
#pragma unroll
    for (int n = 0; n < 4; ++n)
      bfr[n] = *(const bf16x8*)&smB[(wc + n * 16 + lr) * 32 + kcs * 8];
#pragma unroll
    for (int m = 0; m < 4; ++m)
#pragma unroll
      for (int n = 0; n < 4; ++n)
        acc[m][n] = __builtin_amdgcn_mfma_f32_16x16x32_bf16(af[m], bfr[n], acc[m][n], 0, 0, 0);
    __syncthreads();
  }

#pragma unroll
  for (int m = 0; m < 4; ++m)
#pragma unroll
    for (int n = 0; n < 4; ++n)
#pragma unroll
      for (int j = 0; j < 4; ++j) {
        long grow = rowBase + wr + m * 16 + kc * 4 + j;
        long gcol = colBase + wc + n * 16 + lr;
        float v = acc[m][n][j];
        if (EPI == 2) {
          float t = v + w0[gcol];
          float d = (t > 20.f) ? t : __logf(1.f + __expf(t));
          o0[grow * DM + gcol] = f2bf(d);
        } else {  // EPI == 3
          if (gcol < 64) o0[grow * 64 + gcol] = f2bf(v);
          if (gcol == 48) C[grow * 2 + 0] = v;
          if (gcol == 49) C[grow * 2 + 1] = v;
        }
      }
}

// ---------------- selective scan (N_STATE=1), chunked 3-pass, 2 channels/thread ----
__global__ __launch_bounds__(384)
void scan1_k(const u16* __restrict__ deltab, const u16* __restrict__ xcb,
             const float* __restrict__ bmc, const float* __restrict__ A_log,
             float* __restrict__ aprod, float* __restrict__ hend) {
  int pe = threadIdx.x;
  int b = blockIdx.x, c = blockIdx.y;
  int e0 = pe * 2;
  float Ae0 = -__expf(A_log[e0]), Ae1 = -__expf(A_log[e0 + 1]);
  float ap0 = 1.f, h0 = 0.f, ap1 = 1.f, h1 = 0.f;
  long base = (long)b * LSEQ + (long)c * CL;
  for (int i = 0; i < CL; ++i) {
    long t = base + i;
    u32 dv = *(const u32*)&deltab[t * DM + e0];
    u32 xv = *(const u32*)&xcb[t * DM + e0];
    float Bm = bmc[t * 2];
    float d0 = bf2f(dv), d1 = bf2f(dv >> 16);
    float x0 = bf2f(xv), x1 = bf2f(xv >> 16);
    float a0 = __expf(d0 * Ae0), a1 = __expf(d1 * Ae1);
    ap0 *= a0; h0 = a0 * h0 + d0 * Bm * x0;
    ap1 *= a1; h1 = a1 * h1 + d1 * Bm * x1;
  }
  long chain = (long)c * NCHAIN + b * DM + e0;
  *(float2*)&aprod[chain] = make_float2(ap0, ap1);
  *(float2*)&hend[chain]  = make_float2(h0, h1);
}

__global__ __launch_bounds__(256)
void scan2_k(const float* __restrict__ aprod, const float* __restrict__ hend,
             float* __restrict__ carry) {
  int chain = blockIdx.x * 256 + threadIdx.x;
  float h = 0.f;
  for (int c = 0; c < NC; ++c) {
    carry[c * NCHAIN + chain] = h;
    h = aprod[c * NCHAIN + chain] * h + hend[c * NCHAIN + chain];
  }
}

__global__ __launch_bounds__(384)
void scan3_k(const u16* __restrict__ deltab, const u16* __restrict__ xcb,
             const float* __restrict__ bmc, const float* __restrict__ A_log,
             const float* __restrict__ Dp, const u16* __restrict__ szb,
             const float* __restrict__ carry, u16* __restrict__ ybf) {
  int pe = threadIdx.x;
  int b = blockIdx.x, c = blockIdx.y;
  int e0 = pe * 2;
  float Ae0 = -__expf(A_log[e0]), Ae1 = -__expf(A_log[e0 + 1]);
  float De0 = Dp[e0], De1 = Dp[e0 + 1];
  long chain = (long)c * NCHAIN + b * DM + e0;
  float2 hc = *(const float2*)&carry[chain];
  float h0 = hc.x, h1 = hc.y;
  long base = (long)b * LSEQ + (long)c * CL;
  for (int i = 0; i < CL; ++i) {
    long t = base + i;
    u32 dv = *(const u32*)&deltab[t * DM + e0];
    u32 xv = *(const u32*)&xcb[t * DM + e0];
    u32 sv = *(const u32*)&szb[t * DM + e0];
    float Bm = bmc[t * 2], Cc = bmc[t * 2 + 1];
    float d0 = bf2f(dv), d1 = bf2f(dv >> 16);
    float x0 = bf2f(xv), x1 = bf2f(xv >> 16);
    float a0 = __expf(d0 * Ae0), a1 = __expf(d1 * Ae1);
    h0 = a0 * h0 + d0 * Bm * x0;
    h1 = a1 * h1 + d1 * Bm * x1;
    float y0 = (h0 * Cc + De0 * x0) * bf2f(sv);
    float y1 = (h1 * Cc + De1 * x1) * bf2f(sv >> 16);
    *(u32*)&ybf[t * DM + e0] = (u32)f2bf(y0) | ((u32)f2bf(y1) << 16);
  }
}

// ---------------- launch ----------------
extern "C" void kernel_launch(void* const* d_in, const int* in_sizes, int n_in,
                              void* d_out, int out_size, void* d_ws, size_t ws_size,
                              hipStream_t stream) {
  const float* x         = (const float*)d_in[0];
  const float* rms_w     = (const float*)d_in[1];
  const float* in_proj_w = (const float*)d_in[2];
  const float* conv_w    = (const float*)d_in[3];
  const float* conv_b    = (const float*)d_in[4];
  const float* x_proj_w  = (const float*)d_in[5];
  const float* dt_proj_w = (const float*)d_in[6];
  const float* dt_proj_b = (const float*)d_in[7];
  const float* A_log     = (const float*)d_in[8];
  const float* Dp        = (const float*)d_in[9];
  const float* out_proj_w= (const float*)d_in[10];
  float* out = (float*)d_out;

  char* ws = (char*)d_ws;
  size_t off = 0;
  auto alloc = [&](size_t bytes) -> void* {
    void* p = ws + off;
    off += (bytes + 255) & ~(size_t)255;
    return p;
  };
  u16*   xnb    = (u16*)alloc((size_t)TOK * DM * 2);
  u16*   xcb    = (u16*)alloc((size_t)TOK * DM * 2);
  u16*   szb    = (u16*)alloc((size_t)TOK * DM * 2);
  u16*   ybf    = (u16*)alloc((size_t)TOK * DM * 2);
  u16*   deltab = (u16*)alloc((size_t)TOK * DM * 2);
  u16*   dbcb   = (u16*)alloc((size_t)TOK * 64 * 2);
  float* bmc    = (float*)alloc((size_t)TOK * 2 * 4);
  u16*   wInB   = (u16*)alloc((size_t)1536 * 768 * 2);
  u16*   wXpB   = (u16*)alloc((size_t)128 * 768 * 2);
  u16*   wDtB   = (u16*)alloc((size_t)768 * 64 * 2);
  u16*   wOutB  = (u16*)alloc((size_t)768 * 768 * 2);
  float* aprod  = (float*)alloc((size_t)NC * NCHAIN * 4);
  float* hend   = (float*)alloc((size_t)NC * NCHAIN * 4);
  float* carry  = (float*)alloc((size_t)NC * NCHAIN * 4);

  cvt_k<<<(1536 * 768 + 255) / 256, 256, 0, stream>>>(in_proj_w, wInB, 1536 * 768);
  cvt_k<<<(768 * 768 + 255) / 256, 256, 0, stream>>>(out_proj_w, wOutB, 768 * 768);
  cvt_pad_k<<<(128 * 768 + 255) / 256, 256, 0, stream>>>(x_proj_w, wXpB, 50, 768, 768, 128 * 768);
  cvt_pad_k<<<(768 * 64 + 255) / 256, 256, 0, stream>>>(dt_proj_w, wDtB, 768, 48, 64, 768 * 64);

  rmsnorm_k<<<TOK, 192, 0, stream>>>(x, rms_w, xnb);

  // xz = xn @ in_proj_w^T ; fused conv+silu -> xcb, silu(z) -> szb
  gemm64<1><<<dim3(1536 / 128, TOK / 128), 256, 0, stream>>>(
      xnb, wInB, nullptr, conv_w, conv_b, xcb, szb);

  // dbc = xc @ x_proj_w^T (rank-50, N padded to 128): delta_raw cols 0..47 -> dbcb,
  // Bm/C (cols 48/49) -> bmc
  gemm_bt<3><<<dim3(1, TOK / 128), 256, 0, stream>>>(
      xcb, DM, wXpB, DM, DM, bmc, nullptr, dbcb);

  // delta = softplus(dbc48 @ dt_proj_w^T + dt_b) -> bf16
  gemm_bt<2><<<dim3(768 / 128, TOK / 128), 256, 0, stream>>>(
      dbcb, 64, wDtB, 64, 64, nullptr, dt_proj_b, deltab);

  scan1_k<<<dim3(8, NC), 384, 0, stream>>>(deltab, xcb, bmc, A_log, aprod, hend);
  scan2_k<<<NCHAIN / 256, 256, 0, stream>>>(aprod, hend, carry);
  scan3_k<<<dim3(8, NC), 384, 0, stream>>>(deltab, xcb, bmc, A_log, Dp, szb, carry, ybf);

  // out = (y * silu(z)) @ out_proj_w^T
  gemm64<0><<<dim3(768 / 128, TOK / 128), 256, 0, stream>>>(
      ybf, wOutB, out, nullptr, nullptr, nullptr, nullptr);
}

// Round 6
// 343.936 us; speedup vs baseline: 2.4579x; 1.1102x over previous
//
#include <hip/hip_runtime.h>

#define TOK   32768
#define DM    768
#define KDIM  768
#define LSEQ  4096
#define NC    64
#define CL    64
#define NCHAIN 6144

typedef __bf16 bf16x8 __attribute__((ext_vector_type(8)));
typedef float  f32x4  __attribute__((ext_vector_type(4)));
typedef unsigned short u16;
typedef unsigned int u32;

__device__ __forceinline__ u16 f2bf(float f) {
  unsigned u = __builtin_bit_cast(unsigned, f);
  u += 0x7fffu + ((u >> 16) & 1u);
  return (u16)(u >> 16);
}
__device__ __forceinline__ float bf2f(u32 h) {
  unsigned u = (h & 0xffffu) << 16;
  return __builtin_bit_cast(float, u);
}

#define GLOAD_LDS16(g, l) __builtin_amdgcn_global_load_lds( \
    (const __attribute__((address_space(1))) void*)(g),     \
    (__attribute__((address_space(3))) void*)(l), 16, 0, 0)

// ---------------- fp32 -> bf16 weight convert ----------------
__global__ void cvt_k(const float* __restrict__ src, u16* __restrict__ dst, int n) {
  int i = blockIdx.x * 256 + threadIdx.x;
  if (i < n) dst[i] = f2bf(src[i]);
}

// ---------------- fp32 -> bf16 with zero padding ----------------
__global__ void cvt_pad_k(const float* __restrict__ src, u16* __restrict__ dst,
                          int rows, int cols, int dcols, int n) {
  int i = blockIdx.x * 256 + threadIdx.x;
  if (i >= n) return;
  int r = i / dcols, c = i % dcols;
  dst[i] = (r < rows && c < cols) ? f2bf(src[r * cols + c]) : (u16)0;
}

// ---------------- RMSNorm: x (fp32) -> xn (bf16), float4 path ----------------
__global__ __launch_bounds__(192)
void rmsnorm_k(const float* __restrict__ x, const float* __restrict__ w,
               u16* __restrict__ xnb) {
  long t = blockIdx.x;
  int tid = threadIdx.x;
  float4 v = ((const float4*)x)[t * 192 + tid];
  float s = v.x * v.x + v.y * v.y + v.z * v.z + v.w * v.w;
#pragma unroll
  for (int o = 32; o; o >>= 1) s += __shfl_down(s, o, 64);
  __shared__ float red[3];
  if ((tid & 63) == 0) red[tid >> 6] = s;
  __syncthreads();
  float sc = rsqrtf((red[0] + red[1] + red[2]) * (1.f / 768.f) + 1e-6f);
  float4 ww = ((const float4*)w)[tid];
  ushort4 o;
  o.x = f2bf(v.x * sc * ww.x);
  o.y = f2bf(v.y * sc * ww.y);
  o.z = f2bf(v.z * sc * ww.z);
  o.w = f2bf(v.w * sc * ww.w);
  ((ushort4*)xnb)[t * 192 + tid] = o;
}

// ---------------- BK=32 MFMA GEMM, double-buffered, XCD-chunked swizzle ----------
// C[m][n] = sum_k A[m][k]*B[n][k]; A,B bf16 row-major (lda/ldb), K % 32 == 0.
// BM=BN=128, 256 thr = 4 waves (2x2), wave = 64x64 (4x4 frags).
// LDS: 2 buffers x (8KB A + 8KB B) = 32KB. Conflict swizzle (both-sides, rule 21):
// phys 16B slot = logical ^ ((row>>1)&3), pre-applied on global source + ds_read.
// Pipeline (T3 minimum): STAGE(t+1) issued BEFORE compute(t); one __syncthreads
// per K-step drains it after the compute phase has covered most of the latency.
// Block swizzle (T1): 1-D grid; xcd = bid&7 owns a contiguous row-panel band,
// iterating GX column panels per row panel -> A panel L2-reuse, B L2-resident.
// EPI: 0 fp32 C; 1 in_proj (conv+silu->o0, silu(z)->o1);
//      2 dt (bias+softplus->o0 bf16); 3 x_proj (cols<64->o0 ld 64, 48/49->C fp32).
template <int EPI>
__global__ __launch_bounds__(256)
void gemm32(const u16* __restrict__ A, int lda,
            const u16* __restrict__ B, int ldb, int K,
            int GX, int RPX,
            float* __restrict__ C,
            const float* __restrict__ w0, const float* __restrict__ w1,
            u16* __restrict__ o0, u16* __restrict__ o1) {
  __shared__ __align__(16) u16 smA[2 * 4096];
  __shared__ __align__(16) u16 smB[2 * 4096];
  const int tid = threadIdx.x;
  const int lane = tid & 63;
  const int wid = tid >> 6;

  const int bid = blockIdx.x;
  const int xcd = bid & 7;
  const int p = bid >> 3;
  const int colp = p % GX;
  const int rowp = xcd * RPX + p / GX;
  const long rowBase = (long)rowp * 128;
  const long colBase = (long)colp * 128;

  const int wr = (wid >> 1) * 64;
  const int wc = (wid & 1) * 64;
  const int lr = lane & 15;
  const int kc = lane >> 4;
  const int kcs = kc ^ ((lr >> 1) & 3);   // swizzled 16B slot for ds_read

  const int c1 = tid + 256;
  const u16* gA0 = A + (rowBase + (tid >> 2)) * lda + ((tid & 3) ^ ((tid >> 3) & 3)) * 8;
  const u16* gA1 = A + (rowBase + (c1 >> 2)) * lda + ((c1 & 3) ^ ((c1 >> 3) & 3)) * 8;
  const u16* gB0 = B + (colBase + (tid >> 2)) * ldb + ((tid & 3) ^ ((tid >> 3) & 3)) * 8;
  const u16* gB1 = B + (colBase + (c1 >> 2)) * ldb + ((c1 & 3) ^ ((c1 >> 3) & 3)) * 8;

  f32x4 acc[4][4] = {};
  const int NT = K >> 5;

  auto STAGE = [&](int buf, int kt) {
    u16* bA = smA + buf * 4096;
    u16* bB = smB + buf * 4096;
    GLOAD_LDS16(gA0 + kt, &bA[tid * 8]);
    GLOAD_LDS16(gA1 + kt, &bA[c1 * 8]);
    GLOAD_LDS16(gB0 + kt, &bB[tid * 8]);
    GLOAD_LDS16(gB1 + kt, &bB[c1 * 8]);
  };

  STAGE(0, 0);
  __syncthreads();

  for (int t = 0; t < NT; ++t) {
    if (t + 1 < NT) STAGE((t + 1) & 1, (t + 1) << 5);   // issue next-tile loads first
    const u16* cA = smA + (t & 1) * 4096;
    const u16* cB = smB + (t & 1) * 4096;
    bf16x8 af[4], bfr[4];
#pragma unroll
    for (int m = 0; m < 4; ++m)
      af[m] = *(const bf16x8*)&cA[(wr + m * 16 + lr) * 32 + kcs * 8];
#pragma unroll
    for (int n = 0; n < 4; ++n)
      bfr[n] = *(const bf16x8*)&cB[(wc + n * 16 + lr) * 32 + kcs * 8];
#pragma unroll
    for (int m = 0; m < 4; ++m)
#pragma unroll
      for (int n = 0; n < 4; ++n)
        acc[m][n] = __builtin_amdgcn_mfma_f32_16x16x32_bf16(af[m], bfr[n], acc[m][n], 0, 0, 0);
    __syncthreads();   // drains next-tile loads (flew during compute) + LDS reads
  }

#pragma unroll
  for (int m = 0; m < 4; ++m)
#pragma unroll
    for (int n = 0; n < 4; ++n)
#pragma unroll
      for (int j = 0; j < 4; ++j) {
        long grow = rowBase + wr + m * 16 + kc * 4 + j;
        long gcol = colBase + wc + n * 16 + lr;
        float v = acc[m][n][j];
        if (EPI == 0) {
          C[grow * DM + gcol] = v;
        } else if (EPI == 1) {
          if (gcol < DM) {
            float t = v * w0[gcol] + w1[gcol];
            o0[grow * DM + gcol] = f2bf(t / (1.f + __expf(-t)));
          } else {
            o1[grow * DM + (gcol - DM)] = f2bf(v / (1.f + __expf(-v)));
          }
        } else if (EPI == 2) {
          float t = v + w0[gcol];
          float d = (t > 20.f) ? t : __logf(1.f + __expf(t));
          o0[grow * DM + gcol] = f2bf(d);
        } else {  // EPI == 3
          if (gcol < 64) o0[grow * 64 + gcol] = f2bf(v);
          if (gcol == 48) C[grow * 2 + 0] = v;
          if (gcol == 49) C[grow * 2 + 1] = v;
        }
      }
}

// ---------------- selective scan (N_STATE=1), chunked 3-pass, 2 channels/thread ----
__global__ __launch_bounds__(384)
void scan1_k(const u16* __restrict__ deltab, const u16* __restrict__ xcb,
             const float* __restrict__ bmc, const float* __restrict__ A_log,
             float* __restrict__ aprod, float* __restrict__ hend) {
  int pe = threadIdx.x;
  int b = blockIdx.x, c = blockIdx.y;
  int e0 = pe * 2;
  float Ae0 = -__expf(A_log[e0]), Ae1 = -__expf(A_log[e0 + 1]);
  float ap0 = 1.f, h0 = 0.f, ap1 = 1.f, h1 = 0.f;
  long base = (long)b * LSEQ + (long)c * CL;
  for (int i = 0; i < CL; ++i) {
    long t = base + i;
    u32 dv = *(const u32*)&deltab[t * DM + e0];
    u32 xv = *(const u32*)&xcb[t * DM + e0];
    float Bm = bmc[t * 2];
    float d0 = bf2f(dv), d1 = bf2f(dv >> 16);
    float x0 = bf2f(xv), x1 = bf2f(xv >> 16);
    float a0 = __expf(d0 * Ae0), a1 = __expf(d1 * Ae1);
    ap0 *= a0; h0 = a0 * h0 + d0 * Bm * x0;
    ap1 *= a1; h1 = a1 * h1 + d1 * Bm * x1;
  }
  long chain = (long)c * NCHAIN + b * DM + e0;
  *(float2*)&aprod[chain] = make_float2(ap0, ap1);
  *(float2*)&hend[chain]  = make_float2(h0, h1);
}

__global__ __launch_bounds__(256)
void scan2_k(const float* __restrict__ aprod, const float* __restrict__ hend,
             float* __restrict__ carry) {
  int chain = blockIdx.x * 256 + threadIdx.x;
  float h = 0.f;
  for (int c = 0; c < NC; ++c) {
    carry[c * NCHAIN + chain] = h;
    h = aprod[c * NCHAIN + chain] * h + hend[c * NCHAIN + chain];
  }
}

__global__ __launch_bounds__(384)
void scan3_k(const u16* __restrict__ deltab, const u16* __restrict__ xcb,
             const float* __restrict__ bmc, const float* __restrict__ A_log,
             const float* __restrict__ Dp, const u16* __restrict__ szb,
             const float* __restrict__ carry, u16* __restrict__ ybf) {
  int pe = threadIdx.x;
  int b = blockIdx.x, c = blockIdx.y;
  int e0 = pe * 2;
  float Ae0 = -__expf(A_log[e0]), Ae1 = -__expf(A_log[e0 + 1]);
  float De0 = Dp[e0], De1 = Dp[e0 + 1];
  long chain = (long)c * NCHAIN + b * DM + e0;
  float2 hc = *(const float2*)&carry[chain];
  float h0 = hc.x, h1 = hc.y;
  long base = (long)b * LSEQ + (long)c * CL;
  for (int i = 0; i < CL; ++i) {
    long t = base + i;
    u32 dv = *(const u32*)&deltab[t * DM + e0];
    u32 xv = *(const u32*)&xcb[t * DM + e0];
    u32 sv = *(const u32*)&szb[t * DM + e0];
    float Bm = bmc[t * 2], Cc = bmc[t * 2 + 1];
    float d0 = bf2f(dv), d1 = bf2f(dv >> 16);
    float x0 = bf2f(xv), x1 = bf2f(xv >> 16);
    float a0 = __expf(d0 * Ae0), a1 = __expf(d1 * Ae1);
    h0 = a0 * h0 + d0 * Bm * x0;
    h1 = a1 * h1 + d1 * Bm * x1;
    float y0 = (h0 * Cc + De0 * x0) * bf2f(sv);
    float y1 = (h1 * Cc + De1 * x1) * bf2f(sv >> 16);
    *(u32*)&ybf[t * DM + e0] = (u32)f2bf(y0) | ((u32)f2bf(y1) << 16);
  }
}

// ---------------- launch ----------------
extern "C" void kernel_launch(void* const* d_in, const int* in_sizes, int n_in,
                              void* d_out, int out_size, void* d_ws, size_t ws_size,
                              hipStream_t stream) {
  const float* x         = (const float*)d_in[0];
  const float* rms_w     = (const float*)d_in[1];
  const float* in_proj_w = (const float*)d_in[2];
  const float* conv_w    = (const float*)d_in[3];
  const float* conv_b    = (const float*)d_in[4];
  const float* x_proj_w  = (const float*)d_in[5];
  const float* dt_proj_w = (const float*)d_in[6];
  const float* dt_proj_b = (const float*)d_in[7];
  const float* A_log     = (const float*)d_in[8];
  const float* Dp        = (const float*)d_in[9];
  const float* out_proj_w= (const float*)d_in[10];
  float* out = (float*)d_out;

  char* ws = (char*)d_ws;
  size_t off = 0;
  auto alloc = [&](size_t bytes) -> void* {
    void* p = ws + off;
    off += (bytes + 255) & ~(size_t)255;
    return p;
  };
  u16*   xnb    = (u16*)alloc((size_t)TOK * DM * 2);
  u16*   xcb    = (u16*)alloc((size_t)TOK * DM * 2);
  u16*   szb    = (u16*)alloc((size_t)TOK * DM * 2);
  u16*   ybf    = (u16*)alloc((size_t)TOK * DM * 2);
  u16*   deltab = (u16*)alloc((size_t)TOK * DM * 2);
  u16*   dbcb   = (u16*)alloc((size_t)TOK * 64 * 2);
  float* bmc    = (float*)alloc((size_t)TOK * 2 * 4);
  u16*   wInB   = (u16*)alloc((size_t)1536 * 768 * 2);
  u16*   wXpB   = (u16*)alloc((size_t)128 * 768 * 2);
  u16*   wDtB   = (u16*)alloc((size_t)768 * 64 * 2);
  u16*   wOutB  = (u16*)alloc((size_t)768 * 768 * 2);
  float* aprod  = (float*)alloc((size_t)NC * NCHAIN * 4);
  float* hend   = (float*)alloc((size_t)NC * NCHAIN * 4);
  float* carry  = (float*)alloc((size_t)NC * NCHAIN * 4);

  cvt_k<<<(1536 * 768 + 255) / 256, 256, 0, stream>>>(in_proj_w, wInB, 1536 * 768);
  cvt_k<<<(768 * 768 + 255) / 256, 256, 0, stream>>>(out_proj_w, wOutB, 768 * 768);
  cvt_pad_k<<<(128 * 768 + 255) / 256, 256, 0, stream>>>(x_proj_w, wXpB, 50, 768, 768, 128 * 768);
  cvt_pad_k<<<(768 * 64 + 255) / 256, 256, 0, stream>>>(dt_proj_w, wDtB, 768, 48, 64, 768 * 64);

  rmsnorm_k<<<TOK, 192, 0, stream>>>(x, rms_w, xnb);

  // xz = xn @ in_proj_w^T ; fused conv+silu -> xcb, silu(z) -> szb
  // grid 3072 = 8 XCDs x 32 row-panels x 12 col-panels
  gemm32<1><<<3072, 256, 0, stream>>>(
      xnb, DM, wInB, DM, KDIM, 12, 32, nullptr, conv_w, conv_b, xcb, szb);

  // dbc = xc @ x_proj_w^T (rank-50, N pad 128): delta_raw -> dbcb, Bm/C -> bmc
  // grid 256 = 8 x 32 x 1
  gemm32<3><<<256, 256, 0, stream>>>(
      xcb, DM, wXpB, DM, KDIM, 1, 32, bmc, nullptr, nullptr, dbcb, nullptr);

  // delta = softplus(dbc48 @ dt_proj_w^T + dt_b) -> bf16; grid 1536 = 8 x 32 x 6
  gemm32<2><<<1536, 256, 0, stream>>>(
      dbcb, 64, wDtB, 64, 64, 6, 32, nullptr, dt_proj_b, nullptr, deltab, nullptr);

  scan1_k<<<dim3(8, NC), 384, 0, stream>>>(deltab, xcb, bmc, A_log, aprod, hend);
  scan2_k<<<NCHAIN / 256, 256, 0, stream>>>(aprod, hend, carry);
  scan3_k<<<dim3(8, NC), 384, 0, stream>>>(deltab, xcb, bmc, A_log, Dp, szb, carry, ybf);

  // out = (y * silu(z)) @ out_proj_w^T; grid 1536 = 8 x 32 x 6
  gemm32<0><<<1536, 256, 0, stream>>>(
      ybf, DM, wOutB, DM, KDIM, 6, 32, out, nullptr, nullptr, nullptr, nullptr);
}

// Round 7
// 328.878 us; speedup vs baseline: 2.5704x; 1.0458x over previous
//
#include <hip/hip_runtime.h>

#define TOK   32768
#define DM    768
#define KDIM  768
#define LSEQ  4096
#define NC    64
#define CL    64
#define NCHAIN 6144

typedef __bf16 bf16x8 __attribute__((ext_vector_type(8)));
typedef float  f32x4  __attribute__((ext_vector_type(4)));
typedef unsigned short u16;
typedef unsigned int u32;

__device__ __forceinline__ u16 f2bf(float f) {
  unsigned u = __builtin_bit_cast(unsigned, f);
  u += 0x7fffu + ((u >> 16) & 1u);
  return (u16)(u >> 16);
}
__device__ __forceinline__ float bf2f(u32 h) {
  unsigned u = (h & 0xffffu) << 16;
  return __builtin_bit_cast(float, u);
}

#define GLOAD_LDS16(g, l) __builtin_amdgcn_global_load_lds( \
    (const __attribute__((address_space(1))) void*)(g),     \
    (__attribute__((address_space(3))) void*)(l), 16, 0, 0)

// ---------------- fp32 -> bf16 weight convert ----------------
__global__ void cvt_k(const float* __restrict__ src, u16* __restrict__ dst, int n) {
  int i = blockIdx.x * 256 + threadIdx.x;
  if (i < n) dst[i] = f2bf(src[i]);
}

// ---------------- fp32 -> bf16 with zero padding ----------------
__global__ void cvt_pad_k(const float* __restrict__ src, u16* __restrict__ dst,
                          int rows, int cols, int dcols, int n) {
  int i = blockIdx.x * 256 + threadIdx.x;
  if (i >= n) return;
  int r = i / dcols, c = i % dcols;
  dst[i] = (r < rows && c < cols) ? f2bf(src[r * cols + c]) : (u16)0;
}

// ---------------- RMSNorm: x (fp32) -> xn (bf16), float4 path ----------------
__global__ __launch_bounds__(192)
void rmsnorm_k(const float* __restrict__ x, const float* __restrict__ w,
               u16* __restrict__ xnb) {
  long t = blockIdx.x;
  int tid = threadIdx.x;
  float4 v = ((const float4*)x)[t * 192 + tid];
  float s = v.x * v.x + v.y * v.y + v.z * v.z + v.w * v.w;
#pragma unroll
  for (int o = 32; o; o >>= 1) s += __shfl_down(s, o, 64);
  __shared__ float red[3];
  if ((tid & 63) == 0) red[tid >> 6] = s;
  __syncthreads();
  float sc = rsqrtf((red[0] + red[1] + red[2]) * (1.f / 768.f) + 1e-6f);
  float4 ww = ((const float4*)w)[tid];
  ushort4 o;
  o.x = f2bf(v.x * sc * ww.x);
  o.y = f2bf(v.y * sc * ww.y);
  o.z = f2bf(v.z * sc * ww.z);
  o.w = f2bf(v.w * sc * ww.w);
  ((ushort4*)xnb)[t * 192 + tid] = o;
}

// ---------------- BK=32 MFMA GEMM, 3-buffer, distance-2 counted vmcnt ----------
// C[m][n] = sum_k A[m][k]*B[n][k]; A,B bf16 row-major (lda/ldb), K % 32 == 0, NT>=2.
// BM=BN=128, 256 thr = 4 waves (2x2), wave = 64x64 (4x4 frags).
// LDS: 3 x (8KB A + 8KB B) = 48KB. Conflict swizzle (both-sides, rule 21):
// phys 16B slot = logical ^ ((row>>1)&3), pre-applied on global source + ds_read.
// Pipeline (T4): iter t = { ds_read(t); issue STAGE(t+2); MFMA;
// s_waitcnt vmcnt(4) [tile t+1 landed, t+2's 4 loads stay in flight]; s_barrier }.
// Loads get ~2 iterations of flight. Overwrite safety: STAGE(t+2) hits
// buf[(t-1)%3], whose ds_reads completed before the iter-(t-1) barrier.
// Block swizzle (T1): xcd = bid&7 owns a contiguous row-panel band.
// EPI: 0 fp32 C; 1 in_proj (conv+silu->o0, silu(z)->o1);
//      2 dt (bias+softplus->o0 bf16); 3 x_proj (cols<64->o0 ld 64, 48/49->C fp32).
template <int EPI>
__global__ __launch_bounds__(256)
void gemm32(const u16* __restrict__ A, int lda,
            const u16* __restrict__ B, int ldb, int K,
            int GX, int RPX,
            float* __restrict__ C,
            const float* __restrict__ w0, const float* __restrict__ w1,
            u16* __restrict__ o0, u16* __restrict__ o1) {
  __shared__ __align__(16) u16 smA[3 * 4096];
  __shared__ __align__(16) u16 smB[3 * 4096];
  const int tid = threadIdx.x;
  const int lane = tid & 63;
  const int wid = tid >> 6;

  const int bid = blockIdx.x;
  const int xcd = bid & 7;
  const int p = bid >> 3;
  const int colp = p % GX;
  const int rowp = xcd * RPX + p / GX;
  const long rowBase = (long)rowp * 128;
  const long colBase = (long)colp * 128;

  const int wr = (wid >> 1) * 64;
  const int wc = (wid & 1) * 64;
  const int lr = lane & 15;
  const int kc = lane >> 4;
  const int kcs = kc ^ ((lr >> 1) & 3);   // swizzled 16B slot for ds_read

  const int c1 = tid + 256;
  const u16* gA0 = A + (rowBase + (tid >> 2)) * lda + ((tid & 3) ^ ((tid >> 3) & 3)) * 8;
  const u16* gA1 = A + (rowBase + (c1 >> 2)) * lda + ((c1 & 3) ^ ((c1 >> 3) & 3)) * 8;
  const u16* gB0 = B + (colBase + (tid >> 2)) * ldb + ((tid & 3) ^ ((tid >> 3) & 3)) * 8;
  const u16* gB1 = B + (colBase + (c1 >> 2)) * ldb + ((c1 & 3) ^ ((c1 >> 3) & 3)) * 8;

  f32x4 acc[4][4] = {};
  const int NT = K >> 5;

  auto STAGE = [&](int buf, int kt) {
    u16* bA = smA + buf * 4096;
    u16* bB = smB + buf * 4096;
    GLOAD_LDS16(gA0 + kt, &bA[tid * 8]);
    GLOAD_LDS16(gA1 + kt, &bA[c1 * 8]);
    GLOAD_LDS16(gB0 + kt, &bB[tid * 8]);
    GLOAD_LDS16(gB1 + kt, &bB[c1 * 8]);
  };

  STAGE(0, 0);
  STAGE(1, 32);
  asm volatile("s_waitcnt vmcnt(4)" ::: "memory");  // tile 0 landed; tile 1 in flight
  __builtin_amdgcn_s_barrier();

  for (int t = 0; t < NT; ++t) {
    const u16* cA = smA + (t % 3) * 4096;
    const u16* cB = smB + (t % 3) * 4096;
    bf16x8 af[4], bfr[4];
#pragma unroll
    for (int m = 0; m < 4; ++m)
      af[m] = *(const bf16x8*)&cA[(wr + m * 16 + lr) * 32 + kcs * 8];
#pragma unroll
    for (int n = 0; n < 4; ++n)
      bfr[n] = *(const bf16x8*)&cB[(wc + n * 16 + lr) * 32 + kcs * 8];
    if (t + 2 < NT) STAGE((t + 2) % 3, (t + 2) << 5);
#pragma unroll
    for (int m = 0; m < 4; ++m)
#pragma unroll
      for (int n = 0; n < 4; ++n)
        acc[m][n] = __builtin_amdgcn_mfma_f32_16x16x32_bf16(af[m], bfr[n], acc[m][n], 0, 0, 0);
    if (t + 1 < NT) {
      if (t + 2 < NT) asm volatile("s_waitcnt vmcnt(4) lgkmcnt(0)" ::: "memory");
      else            asm volatile("s_waitcnt vmcnt(0) lgkmcnt(0)" ::: "memory");
      __builtin_amdgcn_s_barrier();
    }
  }

#pragma unroll
  for (int m = 0; m < 4; ++m)
#pragma unroll
    for (int n = 0; n < 4; ++n)
#pragma unroll
      for (int j = 0; j < 4; ++j) {
        long grow = rowBase + wr + m * 16 + kc * 4 + j;
        long gcol = colBase + wc + n * 16 + lr;
        float v = acc[m][n][j];
        if (EPI == 0) {
          C[grow * DM + gcol] = v;
        } else if (EPI == 1) {
          if (gcol < DM) {
            float t = v * w0[gcol] + w1[gcol];
            o0[grow * DM + gcol] = f2bf(t / (1.f + __expf(-t)));
          } else {
            o1[grow * DM + (gcol - DM)] = f2bf(v / (1.f + __expf(-v)));
          }
        } else if (EPI == 2) {
          float t = v + w0[gcol];
          float d = (t > 20.f) ? t : __logf(1.f + __expf(t));
          o0[grow * DM + gcol] = f2bf(d);
        } else {  // EPI == 3
          if (gcol < 64) o0[grow * 64 + gcol] = f2bf(v);
          if (gcol == 48) C[grow * 2 + 0] = v;
          if (gcol == 49) C[grow * 2 + 1] = v;
        }
      }
}

// ---------------- selective scan (N_STATE=1), chunked 3-pass, 2 channels/thread ----
__global__ __launch_bounds__(384)
void scan1_k(const u16* __restrict__ deltab, const u16* __restrict__ xcb,
             const float* __restrict__ bmc, const float* __restrict__ A_log,
             float* __restrict__ aprod, float* __restrict__ hend) {
  int pe = threadIdx.x;
  int b = blockIdx.x, c = blockIdx.y;
  int e0 = pe * 2;
  float Ae0 = -__expf(A_log[e0]), Ae1 = -__expf(A_log[e0 + 1]);
  float ap0 = 1.f, h0 = 0.f, ap1 = 1.f, h1 = 0.f;
  long base = (long)b * LSEQ + (long)c * CL;
  for (int i = 0; i < CL; ++i) {
    long t = base + i;
    u32 dv = *(const u32*)&deltab[t * DM + e0];
    u32 xv = *(const u32*)&xcb[t * DM + e0];
    float Bm = bmc[t * 2];
    float d0 = bf2f(dv), d1 = bf2f(dv >> 16);
    float x0 = bf2f(xv), x1 = bf2f(xv >> 16);
    float a0 = __expf(d0 * Ae0), a1 = __expf(d1 * Ae1);
    ap0 *= a0; h0 = a0 * h0 + d0 * Bm * x0;
    ap1 *= a1; h1 = a1 * h1 + d1 * Bm * x1;
  }
  long chain = (long)c * NCHAIN + b * DM + e0;
  *(float2*)&aprod[chain] = make_float2(ap0, ap1);
  *(float2*)&hend[chain]  = make_float2(h0, h1);
}

__global__ __launch_bounds__(256)
void scan2_k(const float* __restrict__ aprod, const float* __restrict__ hend,
             float* __restrict__ carry) {
  int chain = blockIdx.x * 256 + threadIdx.x;
  float h = 0.f;
  for (int c = 0; c < NC; ++c) {
    carry[c * NCHAIN + chain] = h;
    h = aprod[c * NCHAIN + chain] * h + hend[c * NCHAIN + chain];
  }
}

__global__ __launch_bounds__(384)
void scan3_k(const u16* __restrict__ deltab, const u16* __restrict__ xcb,
             const float* __restrict__ bmc, const float* __restrict__ A_log,
             const float* __restrict__ Dp, const u16* __restrict__ szb,
             const float* __restrict__ carry, u16* __restrict__ ybf) {
  int pe = threadIdx.x;
  int b = blockIdx.x, c = blockIdx.y;
  int e0 = pe * 2;
  float Ae0 = -__expf(A_log[e0]), Ae1 = -__expf(A_log[e0 + 1]);
  float De0 = Dp[e0], De1 = Dp[e0 + 1];
  long chain = (long)c * NCHAIN + b * DM + e0;
  float2 hc = *(const float2*)&carry[chain];
  float h0 = hc.x, h1 = hc.y;
  long base = (long)b * LSEQ + (long)c * CL;
  for (int i = 0; i < CL; ++i) {
    long t = base + i;
    u32 dv = *(const u32*)&deltab[t * DM + e0];
    u32 xv = *(const u32*)&xcb[t * DM + e0];
    u32 sv = *(const u32*)&szb[t * DM + e0];
    float Bm = bmc[t * 2], Cc = bmc[t * 2 + 1];
    float d0 = bf2f(dv), d1 = bf2f(dv >> 16);
    float x0 = bf2f(xv), x1 = bf2f(xv >> 16);
    float a0 = __expf(d0 * Ae0), a1 = __expf(d1 * Ae1);
    h0 = a0 * h0 + d0 * Bm * x0;
    h1 = a1 * h1 + d1 * Bm * x1;
    float y0 = (h0 * Cc + De0 * x0) * bf2f(sv);
    float y1 = (h1 * Cc + De1 * x1) * bf2f(sv >> 16);
    *(u32*)&ybf[t * DM + e0] = (u32)f2bf(y0) | ((u32)f2bf(y1) << 16);
  }
}

// ---------------- launch ----------------
extern "C" void kernel_launch(void* const* d_in, const int* in_sizes, int n_in,
                              void* d_out, int out_size, void* d_ws, size_t ws_size,
                              hipStream_t stream) {
  const float* x         = (const float*)d_in[0];
  const float* rms_w     = (const float*)d_in[1];
  const float* in_proj_w = (const float*)d_in[2];
  const float* conv_w    = (const float*)d_in[3];
  const float* conv_b    = (const float*)d_in[4];
  const float* x_proj_w  = (const float*)d_in[5];
  const float* dt_proj_w = (const float*)d_in[6];
  const float* dt_proj_b = (const float*)d_in[7];
  const float* A_log     = (const float*)d_in[8];
  const float* Dp        = (const float*)d_in[9];
  const float* out_proj_w= (const float*)d_in[10];
  float* out = (float*)d_out;

  char* ws = (char*)d_ws;
  size_t off = 0;
  auto alloc = [&](size_t bytes) -> void* {
    void* p = ws + off;
    off += (bytes + 255) & ~(size_t)255;
    return p;
  };
  u16*   xnb    = (u16*)alloc((size_t)TOK * DM * 2);
  u16*   xcb    = (u16*)alloc((size_t)TOK * DM * 2);
  u16*   szb    = (u16*)alloc((size_t)TOK * DM * 2);
  u16*   ybf    = (u16*)alloc((size_t)TOK * DM * 2);
  u16*   deltab = (u16*)alloc((size_t)TOK * DM * 2);
  u16*   dbcb   = (u16*)alloc((size_t)TOK * 64 * 2);
  float* bmc    = (float*)alloc((size_t)TOK * 2 * 4);
  u16*   wInB   = (u16*)alloc((size_t)1536 * 768 * 2);
  u16*   wXpB   = (u16*)alloc((size_t)128 * 768 * 2);
  u16*   wDtB   = (u16*)alloc((size_t)768 * 64 * 2);
  u16*   wOutB  = (u16*)alloc((size_t)768 * 768 * 2);
  float* aprod  = (float*)alloc((size_t)NC * NCHAIN * 4);
  float* hend   = (float*)alloc((size_t)NC * NCHAIN * 4);
  float* carry  = (float*)alloc((size_t)NC * NCHAIN * 4);

  cvt_k<<<(1536 * 768 + 255) / 256, 256, 0, stream>>>(in_proj_w, wInB, 1536 * 768);
  cvt_k<<<(768 * 768 + 255) / 256, 256, 0, stream>>>(out_proj_w, wOutB, 768 * 768);
  cvt_pad_k<<<(128 * 768 + 255) / 256, 256, 0, stream>>>(x_proj_w, wXpB, 50, 768, 768, 128 * 768);
  cvt_pad_k<<<(768 * 64 + 255) / 256, 256, 0, stream>>>(dt_proj_w, wDtB, 768, 48, 64, 768 * 64);

  rmsnorm_k<<<TOK, 192, 0, stream>>>(x, rms_w, xnb);

  // xz = xn @ in_proj_w^T ; fused conv+silu -> xcb, silu(z) -> szb
  // grid 3072 = 8 XCDs x 32 row-panels x 12 col-panels
  gemm32<1><<<3072, 256, 0, stream>>>(
      xnb, DM, wInB, DM, KDIM, 12, 32, nullptr, conv_w, conv_b, xcb, szb);

  // dbc = xc @ x_proj_w^T (rank-50, N pad 128): delta_raw -> dbcb, Bm/C -> bmc
  gemm32<3><<<256, 256, 0, stream>>>(
      xcb, DM, wXpB, DM, KDIM, 1, 32, bmc, nullptr, nullptr, dbcb, nullptr);

  // delta = softplus(dbc48 @ dt_proj_w^T + dt_b) -> bf16
  gemm32<2><<<1536, 256, 0, stream>>>(
      dbcb, 64, wDtB, 64, 64, 6, 32, nullptr, dt_proj_b, nullptr, deltab, nullptr);

  scan1_k<<<dim3(8, NC), 384, 0, stream>>>(deltab, xcb, bmc, A_log, aprod, hend);
  scan2_k<<<NCHAIN / 256, 256, 0, stream>>>(aprod, hend, carry);
  scan3_k<<<dim3(8, NC), 384, 0, stream>>>(deltab, xcb, bmc, A_log, Dp, szb, carry, ybf);

  // out = (y * silu(z)) @ out_proj_w^T
  gemm32<0><<<1536, 256, 0, stream>>>(
      ybf, DM, wOutB, DM, KDIM, 6, 32, out, nullptr, nullptr, nullptr, nullptr);
}